// Round 15
// baseline (241.187 us; speedup 1.0000x reference)
//
#include <hip/hip_runtime.h>
#include <hip/hip_bf16.h>

#define KS 5
#define NCH 32
#define IMH 256
#define IMW 256
#define TW 32
#define TH 4
#define HALO_W (TW + 4)            // 36
#define HALO_H (TH + 4)            // 8
#define HW (IMH * IMW)
#define NPIX 128                   // pixel slots per block
#define OC_CHUNK 8

#define SLOTS 4                    // tile channel slots per chunk (2 per half)
#define NCHUNK 8
#define SLOT_SZ (HALO_H * HALO_W)  // 288
#define TILE_ELEMS (SLOTS * SLOT_SZ) // 1152
#define LOADS ((TILE_ELEMS + 255) / 256) // 5

__device__ __forceinline__ float sigmoidf_(float x) {
    return 1.0f / (1.0f + __expf(-x));
}

// ---------------------------------------------------------------------------
// CIKA forward, 2 threads per pixel (channel-split). Rationale: R10's 114us
// is latency-bound (VALU 44%, HBM 11%) at a 50% occupancy ceiling that is set
// by the DECOMPOSITION (1 px/thread -> 4096 total waves = 16/CU). Splitting
// channels across 2 threads doubles total waves (28/CU after the 21KB LDS
// cap) for ~1.25x work (KSA MLP + kca duplicated per half; stencils and
// pointwise split cleanly). Register discipline from R3-R10 retained:
// per-channel results retire to LDS columns inside ROLLED chunk loops.
// LDS: tile 4.6K + dwk/td/hvp (aliased) 8K + dwu 8K = 20.5 KB -> 7 blocks/CU.
// ---------------------------------------------------------------------------
__global__ __launch_bounds__(256) void cika_fused(
    const float* __restrict__ lower, const float* __restrict__ upper,
    const float* __restrict__ kca_dw_w, const float* __restrict__ kca_dw_b,
    const float* __restrict__ kca_m1_w, const float* __restrict__ kca_m1_b,
    const float* __restrict__ kca_m2_w, const float* __restrict__ kca_m2_b,
    const float* __restrict__ ksa_dw_w, const float* __restrict__ ksa_dw_b,
    const float* __restrict__ ksa_m1_w, const float* __restrict__ ksa_m1_b,
    const float* __restrict__ ksa_m2_w, const float* __restrict__ ksa_m2_b,
    const float* __restrict__ low_dyn_w, const float* __restrict__ low_dyn_b,
    const float* __restrict__ low_pw_w, const float* __restrict__ low_pw_b,
    const float* __restrict__ up_dw_w, const float* __restrict__ up_dw_b,
    const float* __restrict__ up_pw_w, const float* __restrict__ up_pw_b,
    float* __restrict__ out_low, float* __restrict__ out_up)
{
    __shared__ float tile[TILE_ELEMS];                 //  4608 B
    __shared__ __hip_bfloat16 dwk_td_lds[NCH][NPIX];   //  8 KB: dwk -> td -> hvp
    __shared__ __hip_bfloat16 dwu_lds[NCH][NPIX];      //  8 KB: up_dw result

    const int tid = threadIdx.x;
    const int g   = tid >> 7;            // channel half: 0 -> ch 0..15, 1 -> 16..31
    const int s   = tid & (NPIX - 1);    // pixel slot
    const int tx  = s & (TW - 1);
    const int ty  = s >> 5;              // 0..3
    const int tile_x = blockIdx.x * TW;
    const int tile_y = blockIdx.y * TH;
    const int n = blockIdx.z;
    const int x = tile_x + tx, y = tile_y + ty;
    const int pix = y * IMW + x;

    const float* lob = lower + (size_t)n * NCH * HW;
    const float* upb = upper + (size_t)n * NCH * HW;

    // staging geometry. Tile slots 0,1 hold channels (2ck, 2ck+1); slots 2,3
    // hold (16+2ck, 17+2ck). Per-chunk advance = +2*HW on the same offsets.
    int goff[LOADS];
    bool gok[LOADS];
    #pragma unroll
    for (int l = 0; l < LOADS; ++l) {
        const int idx = tid + l * 256;
        int sl = idx / SLOT_SZ;
        int r  = idx - sl * SLOT_SZ;
        int hy = r / HALO_W, hx = r - hy * HALO_W;
        int gy = tile_y + hy - 2, gx = tile_x + hx - 2;
        int cbase = (sl < 2) ? sl : (14 + sl);   // 0,1,16,17
        gok[l] = (idx < TILE_ELEMS) && (gy >= 0) && (gy < IMH) && (gx >= 0) && (gx < IMW);
        goff[l] = cbase * HW + gy * IMW + gx;
    }

    // ================= Phase 1: upper pass (rolled, depth-1 prefetch) =======
    {
        float pre[LOADS];
        #pragma unroll
        for (int l = 0; l < LOADS; ++l)
            pre[l] = gok[l] ? upb[(size_t)goff[l]] : 0.0f;

        #pragma unroll 1
        for (int ck = 0; ck < NCHUNK; ++ck) {
            __syncthreads();
            #pragma unroll
            for (int l = 0; l < LOADS; ++l) {
                const int idx = tid + l * 256;
                if (idx < TILE_ELEMS) tile[idx] = pre[l];
            }
            __syncthreads();
            if (ck + 1 < NCHUNK) {
                const size_t base = (size_t)(ck + 1) * 2 * HW;
                #pragma unroll
                for (int l = 0; l < LOADS; ++l)
                    pre[l] = gok[l] ? upb[base + goff[l]] : 0.0f;
            }
            #pragma unroll
            for (int cc = 0; cc < 2; ++cc) {
                const int c  = g * 16 + 2 * ck + cc;    // wave-uniform
                const int sl = g * 2 + cc;
                float ak = ksa_dw_b[c];
                float au = up_dw_b[c];
                const float* tp = tile + sl * SLOT_SZ + ty * HALO_W + tx;
                #pragma unroll
                for (int i = 0; i < KS; ++i)
                    #pragma unroll
                    for (int j = 0; j < KS; ++j) {
                        float wv = tp[i * HALO_W + j];
                        ak = fmaf(wv, ksa_dw_w[c * 25 + i * KS + j], ak);
                        au = fmaf(wv, up_dw_w[c * 25 + i * KS + j], au);
                    }
                dwk_td_lds[c][s] = __float2bfloat16(fmaxf(ak, 0.0f));
                dwu_lds[c][s]    = __float2bfloat16(au);
            }
        }
    }
    __syncthreads();   // cross-half dwk visibility for the MLP

    // ================= Phase 2: KSA MLP (duplicated per half) ===============
    float ksa[25];
    {
        float dwk[NCH];
        #pragma unroll
        for (int c = 0; c < NCH; ++c)
            dwk[c] = __bfloat162float(dwk_td_lds[c][s]);
        #pragma unroll
        for (int k = 0; k < 25; ++k) ksa[k] = ksa_m2_b[k];
        for (int h = 0; h < 50; ++h) {
            float hv = ksa_m1_b[h];
            #pragma unroll
            for (int c = 0; c < NCH; ++c)
                hv = fmaf(ksa_m1_w[h * NCH + c], dwk[c], hv);
            hv = fmaxf(hv, 0.0f);
            #pragma unroll
            for (int k = 0; k < 25; ++k)
                ksa[k] = fmaf(ksa_m2_w[k * 50 + h], hv, ksa[k]);
        }
        #pragma unroll
        for (int k = 0; k < 25; ++k) ksa[k] = sigmoidf_(ksa[k]);
    }
    // dwk_td_lds dead as dwk; td overwrites it below. Safe: first td write is
    // after phase-3 chunk-0's second barrier, by which point every thread has
    // passed barrier 1 and therefore finished its phase-2 reads.

    // ================= Phase 3: lower pass (rolled), partial hv8 ============
    float hv8[8];
    #pragma unroll
    for (int h = 0; h < 8; ++h)
        hv8[h] = (g == 0) ? kca_m1_b[h] : 0.0f;   // bias counted once
    {
        float pre[LOADS];
        #pragma unroll
        for (int l = 0; l < LOADS; ++l)
            pre[l] = gok[l] ? lob[(size_t)goff[l]] : 0.0f;

        #pragma unroll 1
        for (int ck = 0; ck < NCHUNK; ++ck) {
            __syncthreads();
            #pragma unroll
            for (int l = 0; l < LOADS; ++l) {
                const int idx = tid + l * 256;
                if (idx < TILE_ELEMS) tile[idx] = pre[l];
            }
            __syncthreads();
            if (ck + 1 < NCHUNK) {
                const size_t base = (size_t)(ck + 1) * 2 * HW;
                #pragma unroll
                for (int l = 0; l < LOADS; ++l)
                    pre[l] = gok[l] ? lob[base + goff[l]] : 0.0f;
            }
            #pragma unroll
            for (int cc = 0; cc < 2; ++cc) {
                const int c  = g * 16 + 2 * ck + cc;
                const int sl = g * 2 + cc;
                float ad = kca_dw_b[c];
                float td = low_dyn_b[c];
                const float* tp = tile + sl * SLOT_SZ + ty * HALO_W + tx;
                #pragma unroll
                for (int i = 0; i < KS; ++i)
                    #pragma unroll
                    for (int j = 0; j < KS; ++j) {
                        float wv = tp[i * HALO_W + j];
                        ad = fmaf(wv, kca_dw_w[c * 25 + i * KS + j], ad);
                        td = fmaf(wv * low_dyn_w[c * 25 + i * KS + j], ksa[i * KS + j], td);
                    }
                ad = fmaxf(ad, 0.0f);
                #pragma unroll
                for (int h = 0; h < 8; ++h)
                    hv8[h] = fmaf(kca_m1_w[h * NCH + c], ad, hv8[h]);
                dwk_td_lds[c][s] = __float2bfloat16(td);
            }
        }
    }
    __syncthreads();   // cross-half td visibility

    // ================= Phase 4: out_low (16 output channels per thread) =====
    {
        float tdv[NCH];
        #pragma unroll
        for (int c = 0; c < NCH; ++c)
            tdv[c] = __bfloat162float(dwk_td_lds[c][s]);
        float* ol = out_low + (size_t)n * NCH * HW + pix;
        #pragma unroll
        for (int og = 0; og < 2; ++og) {
            const int ob = g * 16 + og * OC_CHUNK;
            float acc[OC_CHUNK];
            #pragma unroll
            for (int oo = 0; oo < OC_CHUNK; ++oo)
                acc[oo] = low_pw_b[ob + oo];
            #pragma unroll
            for (int c = 0; c < NCH; ++c)
                #pragma unroll
                for (int oo = 0; oo < OC_CHUNK; ++oo)
                    acc[oo] = fmaf(low_pw_w[(ob + oo) * NCH + c], tdv[c], acc[oo]);
            #pragma unroll
            for (int oo = 0; oo < OC_CHUNK; ++oo)
                ol[(size_t)(ob + oo) * HW] = acc[oo];
        }
    }
    __syncthreads();   // td reads done; hvp may overwrite dwk_td region

    // ================= Phase 5: hv8 exchange + KCA (duplicated) =============
    float kca[NCH];
    {
        __hip_bfloat16* hvp = &dwk_td_lds[0][0];   // [8][256] bf16 = 4KB
        #pragma unroll
        for (int h = 0; h < 8; ++h)
            hvp[h * 256 + tid] = __float2bfloat16(hv8[h]);
        __syncthreads();
        #pragma unroll
        for (int h = 0; h < 8; ++h)
            hv8[h] = fmaxf(hv8[h] + __bfloat162float(hvp[h * 256 + (tid ^ 128)]), 0.0f);
        #pragma unroll
        for (int k = 0; k < NCH; ++k) {
            float a = kca_m2_b[k];
            #pragma unroll
            for (int h = 0; h < 8; ++h)
                a = fmaf(kca_m2_w[k * 8 + h], hv8[h], a);
            kca[k] = sigmoidf_(a);
        }
    }

    // ================= Phase 6: up path (16 output channels per thread) =====
    {
        float t2[NCH];
        #pragma unroll
        for (int c = 0; c < NCH; ++c)
            t2[c] = __bfloat162float(dwu_lds[c][s]) * kca[c];
        float* ou = out_up + (size_t)n * NCH * HW + pix;
        #pragma unroll
        for (int og = 0; og < 2; ++og) {
            const int ob = g * 16 + og * OC_CHUNK;
            float acc[OC_CHUNK];
            #pragma unroll
            for (int oo = 0; oo < OC_CHUNK; ++oo)
                acc[oo] = up_pw_b[ob + oo];
            #pragma unroll
            for (int c = 0; c < NCH; ++c)
                #pragma unroll
                for (int oo = 0; oo < OC_CHUNK; ++oo)
                    acc[oo] = fmaf(up_pw_w[(ob + oo) * NCH + c], t2[c], acc[oo]);
            #pragma unroll
            for (int oo = 0; oo < OC_CHUNK; ++oo)
                ou[(size_t)(ob + oo) * HW] = acc[oo];
        }
    }
}

extern "C" void kernel_launch(void* const* d_in, const int* in_sizes, int n_in,
                              void* d_out, int out_size, void* d_ws, size_t ws_size,
                              hipStream_t stream) {
    const float* lower    = (const float*)d_in[0];
    const float* upper    = (const float*)d_in[1];
    const float* kca_dw_w = (const float*)d_in[2];
    const float* kca_dw_b = (const float*)d_in[3];
    const float* kca_m1_w = (const float*)d_in[4];
    const float* kca_m1_b = (const float*)d_in[5];
    const float* kca_m2_w = (const float*)d_in[6];
    const float* kca_m2_b = (const float*)d_in[7];
    const float* ksa_dw_w = (const float*)d_in[8];
    const float* ksa_dw_b = (const float*)d_in[9];
    const float* ksa_m1_w = (const float*)d_in[10];
    const float* ksa_m1_b = (const float*)d_in[11];
    const float* ksa_m2_w = (const float*)d_in[12];
    const float* ksa_m2_b = (const float*)d_in[13];
    const float* low_dyn_w = (const float*)d_in[14];
    const float* low_dyn_b = (const float*)d_in[15];
    const float* low_pw_w  = (const float*)d_in[16];
    const float* low_pw_b  = (const float*)d_in[17];
    const float* up_dw_w   = (const float*)d_in[18];
    const float* up_dw_b   = (const float*)d_in[19];
    const float* up_pw_w   = (const float*)d_in[20];
    const float* up_pw_b   = (const float*)d_in[21];

    const int N = in_sizes[0] / (NCH * HW);
    float* out_low = (float*)d_out;
    float* out_up  = (float*)d_out + (size_t)N * NCH * HW;

    dim3 grid(IMW / TW, IMH / TH, N);   // (8, 64, N) = 2048 blocks
    cika_fused<<<grid, dim3(256), 0, stream>>>(
        lower, upper,
        kca_dw_w, kca_dw_b, kca_m1_w, kca_m1_b, kca_m2_w, kca_m2_b,
        ksa_dw_w, ksa_dw_b, ksa_m1_w, ksa_m1_b, ksa_m2_w, ksa_m2_b,
        low_dyn_w, low_dyn_b, low_pw_w, low_pw_b,
        up_dw_w, up_dw_b, up_pw_w, up_pw_b,
        out_low, out_up);
}

// Round 16
// 191.304 us; speedup vs baseline: 1.2608x; 1.2608x over previous
//
#include <hip/hip_runtime.h>
#include <hip/hip_bf16.h>

#define KS 5
#define NCH 32
#define IMH 256
#define IMW 256
#define TW 32
#define TH 8
#define HW (IMH * IMW)
#define OC_CHUNK 8

__device__ __forceinline__ float sigmoidf_(float x) {
    return 1.0f / (1.0f + __expf(-x));
}

// ---------------------------------------------------------------------------
// CIKA forward, NO LDS tile staging: 5x5 windows are read directly from
// global memory through L1 (per-block per-channel working set ~1.7KB, 25x
// tap reuse -> L1-resident; guide Common-mistake #7: don't stage what
// caches). This removes ALL barriers, staged loads, and ds_writes of the
// tile -- the lockstep machinery that every R11-R15 restructuring attempt
// kept and that correlated with every regression. Everything else is R10
// verbatim: per-thread LDS result columns (dwk/td aliased + dwu, 32KB,
// same-thread access -> zero __syncthreads in the whole kernel), rolled
// channel loops, online hv8, identical phases 2/4/5/6.
// Boundary: wave-uniform template split -- interior blocks (70%) take
// unchecked pointer+immediate taps; edge blocks clamp + {0,1} mask.
// ---------------------------------------------------------------------------
template<bool EDGE>
__device__ __forceinline__ void cika_body(
    const float* __restrict__ lob, const float* __restrict__ upb,
    const float* __restrict__ kca_dw_w, const float* __restrict__ kca_dw_b,
    const float* __restrict__ kca_m1_w, const float* __restrict__ kca_m1_b,
    const float* __restrict__ kca_m2_w, const float* __restrict__ kca_m2_b,
    const float* __restrict__ ksa_dw_w, const float* __restrict__ ksa_dw_b,
    const float* __restrict__ ksa_m1_w, const float* __restrict__ ksa_m1_b,
    const float* __restrict__ ksa_m2_w, const float* __restrict__ ksa_m2_b,
    const float* __restrict__ low_dyn_w, const float* __restrict__ low_dyn_b,
    const float* __restrict__ low_pw_w, const float* __restrict__ low_pw_b,
    const float* __restrict__ up_dw_w, const float* __restrict__ up_dw_b,
    const float* __restrict__ up_pw_w, const float* __restrict__ up_pw_b,
    float* __restrict__ out_low, float* __restrict__ out_up,
    int n, int x, int y, int tid,
    __hip_bfloat16 (*dwk_td_lds)[256], __hip_bfloat16 (*dwu_lds)[256])
{
    const int pix = y * IMW + x;

    // window geometry (read-only; shared by both passes)
    int rowoff[KS], coloff[KS];
    float rm[KS], cm[KS];
    if (EDGE) {
        #pragma unroll
        for (int i = 0; i < KS; ++i) {
            int gy = y + i - 2;
            rm[i] = (gy >= 0 && gy < IMH) ? 1.0f : 0.0f;
            rowoff[i] = min(max(gy, 0), IMH - 1) * IMW;
        }
        #pragma unroll
        for (int j = 0; j < KS; ++j) {
            int gx = x + j - 2;
            cm[j] = (gx >= 0 && gx < IMW) ? 1.0f : 0.0f;
            coloff[j] = min(max(gx, 0), IMW - 1);
        }
    }
    const int base_off = (y - 2) * IMW + (x - 2);   // valid only when !EDGE

    // ================= Phase 1: upper pass =================
    #pragma unroll 1
    for (int c = 0; c < NCH; ++c) {
        const float* bc = upb + (size_t)c * HW;
        float ak = ksa_dw_b[c];
        float au = up_dw_b[c];
        #pragma unroll
        for (int t = 0; t < 25; ++t) {
            const int i = t / 5, j = t % 5;
            float wv;
            if (EDGE) wv = bc[rowoff[i] + coloff[j]] * rm[i] * cm[j];
            else      wv = bc[base_off + i * IMW + j];
            ak = fmaf(wv, ksa_dw_w[c * 25 + t], ak);
            au = fmaf(wv, up_dw_w[c * 25 + t], au);
        }
        dwk_td_lds[c][tid] = __float2bfloat16(fmaxf(ak, 0.0f));
        dwu_lds[c][tid]    = __float2bfloat16(au);
    }

    // ================= Phase 2: KSA MLP 32->50(relu)->25(sigmoid) ==========
    float ksa[25];
    {
        float dwk[NCH];
        #pragma unroll
        for (int c = 0; c < NCH; ++c)
            dwk[c] = __bfloat162float(dwk_td_lds[c][tid]);
        #pragma unroll
        for (int k = 0; k < 25; ++k) ksa[k] = ksa_m2_b[k];
        for (int h = 0; h < 50; ++h) {
            float hv = ksa_m1_b[h];
            #pragma unroll
            for (int c = 0; c < NCH; ++c)
                hv = fmaf(ksa_m1_w[h * NCH + c], dwk[c], hv);
            hv = fmaxf(hv, 0.0f);
            #pragma unroll
            for (int k = 0; k < 25; ++k)
                ksa[k] = fmaf(ksa_m2_w[k * 50 + h], hv, ksa[k]);
        }
        #pragma unroll
        for (int k = 0; k < 25; ++k) ksa[k] = sigmoidf_(ksa[k]);
    }
    // dwk_td_lds dead as dwk -> reused for td (same-thread columns only).

    // ================= Phase 3: lower pass, online hv8 =====================
    float hv8[8];
    #pragma unroll
    for (int h = 0; h < 8; ++h) hv8[h] = kca_m1_b[h];
    #pragma unroll 1
    for (int c = 0; c < NCH; ++c) {
        const float* bc = lob + (size_t)c * HW;
        float ad = kca_dw_b[c];
        float td = low_dyn_b[c];
        #pragma unroll
        for (int t = 0; t < 25; ++t) {
            const int i = t / 5, j = t % 5;
            float wv;
            if (EDGE) wv = bc[rowoff[i] + coloff[j]] * rm[i] * cm[j];
            else      wv = bc[base_off + i * IMW + j];
            ad = fmaf(wv, kca_dw_w[c * 25 + t], ad);
            td = fmaf(wv * low_dyn_w[c * 25 + t], ksa[t], td);
        }
        ad = fmaxf(ad, 0.0f);
        #pragma unroll
        for (int h = 0; h < 8; ++h)
            hv8[h] = fmaf(kca_m1_w[h * NCH + c], ad, hv8[h]);
        dwk_td_lds[c][tid] = __float2bfloat16(td);
    }

    // ================= Phase 4: out_low = low_pw @ td + b ==================
    {
        float tdv[NCH];
        #pragma unroll
        for (int c = 0; c < NCH; ++c)
            tdv[c] = __bfloat162float(dwk_td_lds[c][tid]);
        float* ol = out_low + (size_t)n * NCH * HW + pix;
        #pragma unroll
        for (int oc = 0; oc < NCH / OC_CHUNK; ++oc) {
            float acc[OC_CHUNK];
            #pragma unroll
            for (int oo = 0; oo < OC_CHUNK; ++oo)
                acc[oo] = low_pw_b[oc * OC_CHUNK + oo];
            #pragma unroll
            for (int c = 0; c < NCH; ++c)
                #pragma unroll
                for (int oo = 0; oo < OC_CHUNK; ++oo)
                    acc[oo] = fmaf(low_pw_w[(oc * OC_CHUNK + oo) * NCH + c], tdv[c], acc[oo]);
            #pragma unroll
            for (int oo = 0; oo < OC_CHUNK; ++oo)
                ol[(size_t)(oc * OC_CHUNK + oo) * HW] = acc[oo];
        }
    }

    // ================= Phase 5: KCA finish =================================
    float kca[NCH];
    #pragma unroll
    for (int h = 0; h < 8; ++h) hv8[h] = fmaxf(hv8[h], 0.0f);
    #pragma unroll
    for (int k = 0; k < NCH; ++k) {
        float a = kca_m2_b[k];
        #pragma unroll
        for (int h = 0; h < 8; ++h)
            a = fmaf(kca_m2_w[k * 8 + h], hv8[h], a);
        kca[k] = sigmoidf_(a);
    }

    // ================= Phase 6: up path ====================================
    {
        float t2[NCH];
        #pragma unroll
        for (int c = 0; c < NCH; ++c)
            t2[c] = __bfloat162float(dwu_lds[c][tid]) * kca[c];
        float* ou = out_up + (size_t)n * NCH * HW + pix;
        #pragma unroll
        for (int oc = 0; oc < NCH / OC_CHUNK; ++oc) {
            float acc[OC_CHUNK];
            #pragma unroll
            for (int oo = 0; oo < OC_CHUNK; ++oo)
                acc[oo] = up_pw_b[oc * OC_CHUNK + oo];
            #pragma unroll
            for (int c = 0; c < NCH; ++c)
                #pragma unroll
                for (int oo = 0; oo < OC_CHUNK; ++oo)
                    acc[oo] = fmaf(up_pw_w[(oc * OC_CHUNK + oo) * NCH + c], t2[c], acc[oo]);
            #pragma unroll
            for (int oo = 0; oo < OC_CHUNK; ++oo)
                ou[(size_t)(oc * OC_CHUNK + oo) * HW] = acc[oo];
        }
    }
}

__global__ __launch_bounds__(256) void cika_fused(
    const float* __restrict__ lower, const float* __restrict__ upper,
    const float* __restrict__ kca_dw_w, const float* __restrict__ kca_dw_b,
    const float* __restrict__ kca_m1_w, const float* __restrict__ kca_m1_b,
    const float* __restrict__ kca_m2_w, const float* __restrict__ kca_m2_b,
    const float* __restrict__ ksa_dw_w, const float* __restrict__ ksa_dw_b,
    const float* __restrict__ ksa_m1_w, const float* __restrict__ ksa_m1_b,
    const float* __restrict__ ksa_m2_w, const float* __restrict__ ksa_m2_b,
    const float* __restrict__ low_dyn_w, const float* __restrict__ low_dyn_b,
    const float* __restrict__ low_pw_w, const float* __restrict__ low_pw_b,
    const float* __restrict__ up_dw_w, const float* __restrict__ up_dw_b,
    const float* __restrict__ up_pw_w, const float* __restrict__ up_pw_b,
    float* __restrict__ out_low, float* __restrict__ out_up)
{
    __shared__ __hip_bfloat16 dwk_td_lds[NCH][256];   // 16 KB
    __shared__ __hip_bfloat16 dwu_lds[NCH][256];      // 16 KB

    const int tid = threadIdx.x;
    const int tx = tid & (TW - 1);
    const int ty = tid >> 5;
    const int tile_x = blockIdx.x * TW;
    const int tile_y = blockIdx.y * TH;
    const int n = blockIdx.z;
    const int x = tile_x + tx, y = tile_y + ty;

    const float* lob = lower + (size_t)n * NCH * HW;
    const float* upb = upper + (size_t)n * NCH * HW;

    const bool edge = (tile_x == 0) || (tile_x == IMW - TW) ||
                      (tile_y == 0) || (tile_y == IMH - TH);
    if (edge)
        cika_body<true>(lob, upb,
            kca_dw_w, kca_dw_b, kca_m1_w, kca_m1_b, kca_m2_w, kca_m2_b,
            ksa_dw_w, ksa_dw_b, ksa_m1_w, ksa_m1_b, ksa_m2_w, ksa_m2_b,
            low_dyn_w, low_dyn_b, low_pw_w, low_pw_b,
            up_dw_w, up_dw_b, up_pw_w, up_pw_b,
            out_low, out_up, n, x, y, tid, dwk_td_lds, dwu_lds);
    else
        cika_body<false>(lob, upb,
            kca_dw_w, kca_dw_b, kca_m1_w, kca_m1_b, kca_m2_w, kca_m2_b,
            ksa_dw_w, ksa_dw_b, ksa_m1_w, ksa_m1_b, ksa_m2_w, ksa_m2_b,
            low_dyn_w, low_dyn_b, low_pw_w, low_pw_b,
            up_dw_w, up_dw_b, up_pw_w, up_pw_b,
            out_low, out_up, n, x, y, tid, dwk_td_lds, dwu_lds);
}

extern "C" void kernel_launch(void* const* d_in, const int* in_sizes, int n_in,
                              void* d_out, int out_size, void* d_ws, size_t ws_size,
                              hipStream_t stream) {
    const float* lower    = (const float*)d_in[0];
    const float* upper    = (const float*)d_in[1];
    const float* kca_dw_w = (const float*)d_in[2];
    const float* kca_dw_b = (const float*)d_in[3];
    const float* kca_m1_w = (const float*)d_in[4];
    const float* kca_m1_b = (const float*)d_in[5];
    const float* kca_m2_w = (const float*)d_in[6];
    const float* kca_m2_b = (const float*)d_in[7];
    const float* ksa_dw_w = (const float*)d_in[8];
    const float* ksa_dw_b = (const float*)d_in[9];
    const float* ksa_m1_w = (const float*)d_in[10];
    const float* ksa_m1_b = (const float*)d_in[11];
    const float* ksa_m2_w = (const float*)d_in[12];
    const float* ksa_m2_b = (const float*)d_in[13];
    const float* low_dyn_w = (const float*)d_in[14];
    const float* low_dyn_b = (const float*)d_in[15];
    const float* low_pw_w  = (const float*)d_in[16];
    const float* low_pw_b  = (const float*)d_in[17];
    const float* up_dw_w   = (const float*)d_in[18];
    const float* up_dw_b   = (const float*)d_in[19];
    const float* up_pw_w   = (const float*)d_in[20];
    const float* up_pw_b   = (const float*)d_in[21];

    const int N = in_sizes[0] / (NCH * HW);
    float* out_low = (float*)d_out;
    float* out_up  = (float*)d_out + (size_t)N * NCH * HW;

    dim3 grid(IMW / TW, IMH / TH, N);   // (8, 32, N) = 1024 blocks
    cika_fused<<<grid, dim3(256), 0, stream>>>(
        lower, upper,
        kca_dw_w, kca_dw_b, kca_m1_w, kca_m1_b, kca_m2_w, kca_m2_b,
        ksa_dw_w, ksa_dw_b, ksa_m1_w, ksa_m1_b, ksa_m2_w, ksa_m2_b,
        low_dyn_w, low_dyn_b, low_pw_w, low_pw_b,
        up_dw_w, up_dw_b, up_pw_w, up_pw_b,
        out_low, out_up);
}

// Round 17
// 114.643 us; speedup vs baseline: 2.1038x; 1.6687x over previous
//
#include <hip/hip_runtime.h>
#include <hip/hip_bf16.h>

#define KS 5
#define NCH 32
#define IMH 256
#define IMW 256
#define TW 32
#define TH 8
#define HALO_W (TW + 4)
#define HALO_H (TH + 4)
#define HW (IMH * IMW)
#define OC_CHUNK 8

#define CHUNK 4
#define NCHUNK (NCH / CHUNK)
#define TILE_ELEMS (CHUNK * HALO_H * HALO_W)
#define LOADS ((TILE_ELEMS + 255) / 256)   // 7

__device__ __forceinline__ float sigmoidf_(float x) {
    return 1.0f / (1.0f + __expf(-x));
}

// ---------------------------------------------------------------------------
// FINAL: fully fused CIKA forward, one kernel. Exact R10 structure
// (measured 113.9-114.7 us, best of 16 rounds; 18x over the first correct
// kernel). Verified counters: VGPR=64 (no spill), LDS=39.9KB (4 blocks/CU,
// grid fully resident), occupancy ~46% (decomposition ceiling: 1 px/thread
// -> 4096 waves = 16/CU), VALUBusy ~44%, zero bank conflicts, hbm_bytes at
// the ~160MB ideal. Eight alternative structures (occupancy+, pk_fma,
// tap-prefetch, depth-2 pipeline, channel-split, L1-direct) all regressed:
// the compiler's schedule of this source is a sharp local optimum.
// Key invariants (violating any reintroduces 256-VGPR spill):
//  - per-channel results retire IMMEDIATELY to per-thread LDS bf16 columns
//  - no register array incrementally written across an UNROLLED staging loop
//  - chunk loops ROLLED (#pragma unroll 1); hv8[8] is plain loop-carried state
//  - depth-1 issue-early prefetch: next chunk's loads issue before compute
// ---------------------------------------------------------------------------
__global__ __launch_bounds__(256) void cika_fused(
    const float* __restrict__ lower, const float* __restrict__ upper,
    const float* __restrict__ kca_dw_w, const float* __restrict__ kca_dw_b,
    const float* __restrict__ kca_m1_w, const float* __restrict__ kca_m1_b,
    const float* __restrict__ kca_m2_w, const float* __restrict__ kca_m2_b,
    const float* __restrict__ ksa_dw_w, const float* __restrict__ ksa_dw_b,
    const float* __restrict__ ksa_m1_w, const float* __restrict__ ksa_m1_b,
    const float* __restrict__ ksa_m2_w, const float* __restrict__ ksa_m2_b,
    const float* __restrict__ low_dyn_w, const float* __restrict__ low_dyn_b,
    const float* __restrict__ low_pw_w, const float* __restrict__ low_pw_b,
    const float* __restrict__ up_dw_w, const float* __restrict__ up_dw_b,
    const float* __restrict__ up_pw_w, const float* __restrict__ up_pw_b,
    float* __restrict__ out_low, float* __restrict__ out_up)
{
    __shared__ float tile[TILE_ELEMS];                 //  6912 B
    __shared__ __hip_bfloat16 dwk_td_lds[NCH][256];    // 16 KB: relu(ksa_dw), later td
    __shared__ __hip_bfloat16 dwu_lds[NCH][256];       // 16 KB: up_dw result

    const int tid = threadIdx.x;
    const int tx = tid & (TW - 1);
    const int ty = tid >> 5;
    const int tile_x = blockIdx.x * TW;
    const int tile_y = blockIdx.y * TH;
    const int n = blockIdx.z;
    const int x = tile_x + tx, y = tile_y + ty;
    const int pix = y * IMW + x;

    const float* lob = lower + (size_t)n * NCH * HW;
    const float* upb = upper + (size_t)n * NCH * HW;

    // hoisted staging geometry (shared by both passes)
    int goff[LOADS];
    bool gok[LOADS];
    #pragma unroll
    for (int l = 0; l < LOADS; ++l) {
        const int idx = tid + l * 256;
        int c = idx / (HALO_H * HALO_W);
        int r = idx - c * (HALO_H * HALO_W);
        int hy = r / HALO_W, hx = r - hy * HALO_W;
        int gy = tile_y + hy - 2, gx = tile_x + hx - 2;
        gok[l] = (idx < TILE_ELEMS) && (gy >= 0) && (gy < IMH) && (gx >= 0) && (gx < IMW);
        goff[l] = c * HW + gy * IMW + gx;
    }

    // ================= Phase 1: upper pass (rolled) =================
    {
        float pre[LOADS];
        #pragma unroll
        for (int l = 0; l < LOADS; ++l)
            pre[l] = gok[l] ? upb[(size_t)0 + goff[l]] : 0.0f;

        #pragma unroll 1
        for (int ck = 0; ck < NCHUNK; ++ck) {
            __syncthreads();
            #pragma unroll
            for (int l = 0; l < LOADS; ++l) {
                const int idx = tid + l * 256;
                if (idx < TILE_ELEMS) tile[idx] = pre[l];
            }
            __syncthreads();
            if (ck + 1 < NCHUNK) {
                const size_t base = (size_t)(ck + 1) * CHUNK * HW;
                #pragma unroll
                for (int l = 0; l < LOADS; ++l)
                    pre[l] = gok[l] ? upb[base + goff[l]] : 0.0f;
            }
            const int c0 = ck * CHUNK;
            #pragma unroll
            for (int cc = 0; cc < CHUNK; ++cc) {
                const int c = c0 + cc;
                float ak = ksa_dw_b[c];
                float au = up_dw_b[c];
                const float* tp = tile + cc * (HALO_H * HALO_W) + ty * HALO_W + tx;
                #pragma unroll
                for (int i = 0; i < KS; ++i)
                    #pragma unroll
                    for (int j = 0; j < KS; ++j) {
                        float wv = tp[i * HALO_W + j];
                        ak = fmaf(wv, ksa_dw_w[c * 25 + i * KS + j], ak);
                        au = fmaf(wv, up_dw_w[c * 25 + i * KS + j], au);
                    }
                dwk_td_lds[c][tid] = __float2bfloat16(fmaxf(ak, 0.0f));
                dwu_lds[c][tid]    = __float2bfloat16(au);
            }
        }
    }

    // ================= Phase 2: KSA MLP 32->50(relu)->25(sigmoid) =================
    float ksa[25];
    {
        float dwk[NCH];
        #pragma unroll
        for (int c = 0; c < NCH; ++c)
            dwk[c] = __bfloat162float(dwk_td_lds[c][tid]);
        #pragma unroll
        for (int k = 0; k < 25; ++k) ksa[k] = ksa_m2_b[k];
        for (int h = 0; h < 50; ++h) {
            float hv = ksa_m1_b[h];
            #pragma unroll
            for (int c = 0; c < NCH; ++c)
                hv = fmaf(ksa_m1_w[h * NCH + c], dwk[c], hv);
            hv = fmaxf(hv, 0.0f);
            #pragma unroll
            for (int k = 0; k < 25; ++k)
                ksa[k] = fmaf(ksa_m2_w[k * 50 + h], hv, ksa[k]);
        }
        #pragma unroll
        for (int k = 0; k < 25; ++k) ksa[k] = sigmoidf_(ksa[k]);
    }
    // dwk_td_lds now dead as dwk -> reused below for td (same-thread
    // column access only, so no barrier needed for the aliasing).

    // ================= Phase 3: lower pass (rolled), online hv8 =================
    float hv8[8];
    #pragma unroll
    for (int h = 0; h < 8; ++h) hv8[h] = kca_m1_b[h];
    {
        float pre[LOADS];
        #pragma unroll
        for (int l = 0; l < LOADS; ++l)
            pre[l] = gok[l] ? lob[(size_t)0 + goff[l]] : 0.0f;

        #pragma unroll 1
        for (int ck = 0; ck < NCHUNK; ++ck) {
            __syncthreads();
            #pragma unroll
            for (int l = 0; l < LOADS; ++l) {
                const int idx = tid + l * 256;
                if (idx < TILE_ELEMS) tile[idx] = pre[l];
            }
            __syncthreads();
            if (ck + 1 < NCHUNK) {
                const size_t base = (size_t)(ck + 1) * CHUNK * HW;
                #pragma unroll
                for (int l = 0; l < LOADS; ++l)
                    pre[l] = gok[l] ? lob[base + goff[l]] : 0.0f;
            }
            const int c0 = ck * CHUNK;
            #pragma unroll
            for (int cc = 0; cc < CHUNK; ++cc) {
                const int c = c0 + cc;
                float ad = kca_dw_b[c];
                float td = low_dyn_b[c];
                const float* tp = tile + cc * (HALO_H * HALO_W) + ty * HALO_W + tx;
                #pragma unroll
                for (int i = 0; i < KS; ++i)
                    #pragma unroll
                    for (int j = 0; j < KS; ++j) {
                        float wv = tp[i * HALO_W + j];
                        ad = fmaf(wv, kca_dw_w[c * 25 + i * KS + j], ad);
                        td = fmaf(wv * low_dyn_w[c * 25 + i * KS + j], ksa[i * KS + j], td);
                    }
                ad = fmaxf(ad, 0.0f);
                #pragma unroll
                for (int h = 0; h < 8; ++h)
                    hv8[h] = fmaf(kca_m1_w[h * NCH + c], ad, hv8[h]);
                dwk_td_lds[c][tid] = __float2bfloat16(td);   // td into aliased array
            }
        }
    }

    // ================= Phase 4: out_low = low_pw @ td + b =================
    {
        float tdv[NCH];
        #pragma unroll
        for (int c = 0; c < NCH; ++c)
            tdv[c] = __bfloat162float(dwk_td_lds[c][tid]);
        float* ol = out_low + (size_t)n * NCH * HW + pix;
        #pragma unroll
        for (int oc = 0; oc < NCH / OC_CHUNK; ++oc) {
            float acc[OC_CHUNK];
            #pragma unroll
            for (int oo = 0; oo < OC_CHUNK; ++oo)
                acc[oo] = low_pw_b[oc * OC_CHUNK + oo];
            #pragma unroll
            for (int c = 0; c < NCH; ++c)
                #pragma unroll
                for (int oo = 0; oo < OC_CHUNK; ++oo)
                    acc[oo] = fmaf(low_pw_w[(oc * OC_CHUNK + oo) * NCH + c], tdv[c], acc[oo]);
            #pragma unroll
            for (int oo = 0; oo < OC_CHUNK; ++oo)
                ol[(size_t)(oc * OC_CHUNK + oo) * HW] = acc[oo];
        }
    }

    // ================= Phase 5: KCA finish =================
    float kca[NCH];
    #pragma unroll
    for (int h = 0; h < 8; ++h) hv8[h] = fmaxf(hv8[h], 0.0f);
    #pragma unroll
    for (int k = 0; k < NCH; ++k) {
        float a = kca_m2_b[k];
        #pragma unroll
        for (int h = 0; h < 8; ++h)
            a = fmaf(kca_m2_w[k * 8 + h], hv8[h], a);
        kca[k] = sigmoidf_(a);
    }

    // ================= Phase 6: up path =================
    {
        float t2[NCH];
        #pragma unroll
        for (int c = 0; c < NCH; ++c)
            t2[c] = __bfloat162float(dwu_lds[c][tid]) * kca[c];
        float* ou = out_up + (size_t)n * NCH * HW + pix;
        #pragma unroll
        for (int oc = 0; oc < NCH / OC_CHUNK; ++oc) {
            float acc[OC_CHUNK];
            #pragma unroll
            for (int oo = 0; oo < OC_CHUNK; ++oo)
                acc[oo] = up_pw_b[oc * OC_CHUNK + oo];
            #pragma unroll
            for (int c = 0; c < NCH; ++c)
                #pragma unroll
                for (int oo = 0; oo < OC_CHUNK; ++oo)
                    acc[oo] = fmaf(up_pw_w[(oc * OC_CHUNK + oo) * NCH + c], t2[c], acc[oo]);
            #pragma unroll
            for (int oo = 0; oo < OC_CHUNK; ++oo)
                ou[(size_t)(oc * OC_CHUNK + oo) * HW] = acc[oo];
        }
    }
}

extern "C" void kernel_launch(void* const* d_in, const int* in_sizes, int n_in,
                              void* d_out, int out_size, void* d_ws, size_t ws_size,
                              hipStream_t stream) {
    const float* lower    = (const float*)d_in[0];
    const float* upper    = (const float*)d_in[1];
    const float* kca_dw_w = (const float*)d_in[2];
    const float* kca_dw_b = (const float*)d_in[3];
    const float* kca_m1_w = (const float*)d_in[4];
    const float* kca_m1_b = (const float*)d_in[5];
    const float* kca_m2_w = (const float*)d_in[6];
    const float* kca_m2_b = (const float*)d_in[7];
    const float* ksa_dw_w = (const float*)d_in[8];
    const float* ksa_dw_b = (const float*)d_in[9];
    const float* ksa_m1_w = (const float*)d_in[10];
    const float* ksa_m1_b = (const float*)d_in[11];
    const float* ksa_m2_w = (const float*)d_in[12];
    const float* ksa_m2_b = (const float*)d_in[13];
    const float* low_dyn_w = (const float*)d_in[14];
    const float* low_dyn_b = (const float*)d_in[15];
    const float* low_pw_w  = (const float*)d_in[16];
    const float* low_pw_b  = (const float*)d_in[17];
    const float* up_dw_w   = (const float*)d_in[18];
    const float* up_dw_b   = (const float*)d_in[19];
    const float* up_pw_w   = (const float*)d_in[20];
    const float* up_pw_b   = (const float*)d_in[21];

    const int N = in_sizes[0] / (NCH * HW);
    float* out_low = (float*)d_out;
    float* out_up  = (float*)d_out + (size_t)N * NCH * HW;

    dim3 grid(IMW / TW, IMH / TH, N);
    cika_fused<<<grid, dim3(256), 0, stream>>>(
        lower, upper,
        kca_dw_w, kca_dw_b, kca_m1_w, kca_m1_b, kca_m2_w, kca_m2_b,
        ksa_dw_w, ksa_dw_b, ksa_m1_w, ksa_m1_b, ksa_m2_w, ksa_m2_b,
        low_dyn_w, low_dyn_b, low_pw_w, low_pw_b,
        up_dw_w, up_dw_b, up_pw_w, up_pw_b,
        out_low, out_up);
}